// Round 1
// baseline (595.591 us; speedup 1.0000x reference)
//
#include <hip/hip_runtime.h>
#include <hip/hip_bf16.h>

// ---------- types ----------
typedef short  bf16x8s __attribute__((ext_vector_type(8)));  // 8 bf16 (4 VGPRs)
typedef float  f32x4   __attribute__((ext_vector_type(4)));  // 4 fp32 acc

#define BATCH 32
#define SEQL  2048
#define NROWS (BATCH * SEQL)   // 65536
#define IN    1024
#define HID   1024

// workspace layout
#define WHB_OFF   0u          // 2 MB   bf16 W_h
#define BIAS_OFF  0x200000u   // 4 KB
#define SPART_OFF 0x210000u   // 4 MB   s partials, ROW-MAJOR [65536][16]
#define ABUF_OFF  0x610000u   // 256 KB softmax weights
#define HB_OFF    0x650000u   // 128 MB bf16 h (written by GEMM cb==0 blocks)
#define WS_NEED_BF16 ((size_t)HB_OFF + (size_t)NROWS * IN * 2)

// pack two fp32 -> two bf16 (round-up-on-half via +0x8000, v_perm byte select)
__device__ __forceinline__ unsigned int pack2bf(float f0, float f1) {
    unsigned int u0 = __float_as_uint(f0) + 0x8000u;
    unsigned int u1 = __float_as_uint(f1) + 0x8000u;
    return __builtin_amdgcn_perm(u1, u0, 0x07060302u);
}

__device__ __forceinline__ float tanh_fast(float x) {
    float xc = fminf(fmaxf(x, -15.f), 15.f);
    float t  = __builtin_amdgcn_exp2f(xc * 2.8853900817779268f); // e^(2x)
    return (t - 1.f) * __builtin_amdgcn_rcpf(t + 1.f);
}

// async 16B global->LDS (DMA; LDS dest = wave-uniform base + lane*16)
__device__ __forceinline__ void gl2lds16(const void* g, void* l) {
    __builtin_amdgcn_global_load_lds(
        (const __attribute__((address_space(1))) unsigned int*)g,
        (__attribute__((address_space(3))) unsigned int*)l, 16, 0, 0);
}

// XCD-locality swizzle: the 8 cb-siblings of a row-block share bi%8 -> same XCD
// (round-robin) -> A row-block L2-resident across re-reads. [R2: FETCH 1.06GB->92MB]
__device__ __forceinline__ void block_map(int bi, int& rb, int& cb) {
    int xcd  = bi & 7;
    int slot = bi >> 3;
    rb = xcd + 8 * (slot >> 3);
    cb = slot & 7;
}

// ---------- kernel 1: W_h->bf16 + bias = ln_b + W_vq@vq  (1024 blocks only) ----------
__global__ __launch_bounds__(256) void prep_kernel(const float* __restrict__ ln_w,
                                                   const float* __restrict__ ln_b,
                                                   const float* __restrict__ vq,
                                                   unsigned short* __restrict__ whb,
                                                   float* __restrict__ bias) {
    const int n    = blockIdx.x;
    const int t    = threadIdx.x;
    const int wave = t >> 6;
    const int lane = t & 63;
    float4 v = ((const float4*)(ln_w + (size_t)n * 2048))[t];
    uint2 pk;
    pk.x = pack2bf(v.x, v.y);
    pk.y = pack2bf(v.z, v.w);
    *(uint2*)(whb + (size_t)n * 1024 + t * 4) = pk;
    const float* wrow = ln_w + (size_t)n * 2048 + 1024;
    float s = 0.f;
    #pragma unroll
    for (int j = 0; j < 4; ++j) {
        int k = t + j * 256;
        s += wrow[k] * vq[k];
    }
    #pragma unroll
    for (int off = 32; off; off >>= 1) s += __shfl_xor(s, off);
    __shared__ float red[4];
    if (lane == 0) red[wave] = s;
    __syncthreads();
    if (t == 0) bias[n] = ln_b[n] + red[0] + red[1] + red[2] + red[3];
}

// ---------- kernel 2: fused bf16 GEMM, BM=256 x BN=128, BK=32, 8 waves ----------
// A is read as f32 from h, packed to bf16 in registers (one-iter prefetch), written
// to swizzled LDS; cb==0 blocks additionally persist the packed A to hb for kernel 4.
// B stays on the proven global_load_lds DMA path from whb.
// epilogue: s_part[row][16] (ROW-MAJOR) = partial of sum_cols tanh(pre+bias)*v_w
__global__ __launch_bounds__(512) void gemm256_fused_kernel(const float* __restrict__ h,
                                                            const unsigned short* __restrict__ whb,
                                                            const float* __restrict__ bias,
                                                            const float* __restrict__ vw,
                                                            float* __restrict__ s_part,
                                                            unsigned short* __restrict__ hb) {
    __shared__ __align__(16) unsigned short As[8192]; // 16 KB: 256 rows x 32 shorts
    __shared__ __align__(16) unsigned short Bs[4096]; // 8 KB : 128 rows x 32 shorts

    const int tid = threadIdx.x;
    int rb, cb;
    block_map(blockIdx.x, rb, cb);
    const int wave = tid >> 6;
    const int lane = tid & 63;
    const int quad = lane >> 4;
    const int l15  = lane & 15;
    const int wy   = wave >> 1;          // 0..3 row band
    const int wx   = wave & 1;           // 0..1 col band
    const int row0 = rb * 256;
    const int col0 = cb * 128;

    // A reg-staging: 256 rows x 32 floats per K-step; 16 floats (half row) per thread.
    // LDS layout identical to the proven DMA kernel: row stride 32 shorts, slot s
    // holds k-group s^swz(row), swz=(row>>1)&3 -> frag-read pointers unchanged.
    const int srow = tid >> 1;           // 0..255
    const int half = tid & 1;            // which 16-float half of the row
    const int aswz = (srow >> 1) & 3;
    const float* gA = h + (size_t)(row0 + srow) * 1024 + half * 16;
    unsigned short* wA0 = As + srow * 32 + (((2 * half)     ^ aswz) * 8);
    unsigned short* wA1 = As + srow * 32 + (((2 * half + 1) ^ aswz) * 8);
    unsigned short* hbp = hb + (size_t)(row0 + srow) * 1024 + half * 16;

    // B DMA staging: 512 threads x 8 shorts = 128 rows x 32 shorts, one issue.
    const int bsrow = tid >> 2;          // 0..127
    const int bsg   = tid & 3;
    const int bswz  = (bsrow >> 1) & 3;
    const unsigned short* gB0 = whb + (size_t)(col0 + bsrow) * 1024 + ((bsg ^ bswz) * 8);
    unsigned short* lB0 = Bs + tid * 8;

    // fragment read pointers (k-invariant; slot = quad ^ ((row>>1)&3))
    const unsigned short* rA[4];
    const unsigned short* rB[4];
    #pragma unroll
    for (int i = 0; i < 4; ++i) {
        int ra = wy * 64 + i * 16 + l15;         // 0..255
        rA[i] = As + ra * 32 + ((quad ^ ((ra >> 1) & 3)) * 8);
        int rn = wx * 64 + i * 16 + l15;         // 0..127
        rB[i] = Bs + rn * 32 + ((quad ^ ((rn >> 1) & 3)) * 8);
    }

    f32x4 acc[4][4];
    #pragma unroll
    for (int i = 0; i < 4; ++i)
        #pragma unroll
        for (int j = 0; j < 4; ++j)
            acc[i][j] = (f32x4){0.f, 0.f, 0.f, 0.f};

    // prologue: prefetch first K-step's A floats
    float4 va0 = *(const float4*)(gA);
    float4 va1 = *(const float4*)(gA + 4);
    float4 va2 = *(const float4*)(gA + 8);
    float4 va3 = *(const float4*)(gA + 12);

    for (int k0 = 0; k0 < 1024; k0 += 32) {
        __syncthreads();                 // prev iter's frag reads complete
        gl2lds16(gB0 + k0, lB0);
        uint4 p0, p1;
        p0.x = pack2bf(va0.x, va0.y); p0.y = pack2bf(va0.z, va0.w);
        p0.z = pack2bf(va1.x, va1.y); p0.w = pack2bf(va1.z, va1.w);
        p1.x = pack2bf(va2.x, va2.y); p1.y = pack2bf(va2.z, va2.w);
        p1.z = pack2bf(va3.x, va3.y); p1.w = pack2bf(va3.z, va3.w);
        *(uint4*)wA0 = p0;
        *(uint4*)wA1 = p1;
        if (cb == 0) {                   // persist packed h for kernel 4 (overlapped)
            *(uint4*)(hbp + k0)     = p0;
            *(uint4*)(hbp + k0 + 8) = p1;
        }
        // prefetch next K-step (wraps harmlessly to 0 on the last iter)
        const int kn = (k0 + 32) & 1023;
        va0 = *(const float4*)(gA + kn);
        va1 = *(const float4*)(gA + kn + 4);
        va2 = *(const float4*)(gA + kn + 8);
        va3 = *(const float4*)(gA + kn + 12);
        __syncthreads();                 // DMA (vmcnt) + ds_writes (lgkm) drained

        bf16x8s af[4], bfv[4];
        #pragma unroll
        for (int i = 0; i < 4; ++i) af[i]  = *(const bf16x8s*)rA[i];
        #pragma unroll
        for (int i = 0; i < 4; ++i) bfv[i] = *(const bf16x8s*)rB[i];
        #pragma unroll
        for (int mt = 0; mt < 4; ++mt)
            #pragma unroll
            for (int nt = 0; nt < 4; ++nt)
                acc[mt][nt] = __builtin_amdgcn_mfma_f32_16x16x32_bf16(af[mt], bfv[nt], acc[mt][nt], 0, 0, 0);
    }

    // epilogue: C/D layout col=lane&15, row=quad*4+r [m89/m91]
    const int colb = col0 + wx * 64 + l15;
    float vwv[4], bv[4];
    #pragma unroll
    for (int nt = 0; nt < 4; ++nt) {
        vwv[nt] = vw[colb + nt * 16];
        bv[nt]  = bias[colb + nt * 16];
    }
    const int rowb = row0 + wy * 64 + quad * 4;
    const int colp = cb * 2 + wx;        // partial slot 0..15
    #pragma unroll
    for (int mt = 0; mt < 4; ++mt) {
        #pragma unroll
        for (int r = 0; r < 4; ++r) {
            float p = 0.f;
            #pragma unroll
            for (int nt = 0; nt < 4; ++nt)
                p += tanh_fast(acc[mt][nt][r] + bv[nt]) * vwv[nt];
            p += __shfl_xor(p, 1);
            p += __shfl_xor(p, 2);
            p += __shfl_xor(p, 4);
            p += __shfl_xor(p, 8);
            if (l15 == 0) s_part[(size_t)(rowb + mt * 16 + r) * 16 + colp] = p;
        }
    }
}

// ---------- kernel 2b: fp32-A fallback (inline pack), only if ws too small ----------
__global__ __launch_bounds__(256) void gemm_f32_kernel(const float* __restrict__ hmat,
                                                       const unsigned short* __restrict__ whb,
                                                       const float* __restrict__ bias,
                                                       const float* __restrict__ vw,
                                                       float* __restrict__ s_part) {
    __shared__ __align__(16) unsigned short As[4096];
    __shared__ __align__(16) unsigned short Bs[4096];
    const int tid = threadIdx.x;
    int rb, cb;
    block_map(blockIdx.x, rb, cb);
    const int wave = tid >> 6;
    const int lane = tid & 63;
    const int quad = lane >> 4;
    const int l15  = lane & 15;
    const int wy   = wave >> 1;
    const int wx   = wave & 1;
    const int row0 = rb * 128;
    const int col0 = cb * 128;
    const int srow = tid >> 2;
    const int sg   = tid & 3;
    const int swz  = (srow >> 1) & 3;
    const float*          gA0 = hmat + (size_t)(row0 + srow)      * 1024 + sg * 8;
    const float*          gA1 = hmat + (size_t)(row0 + srow + 64) * 1024 + sg * 8;
    const unsigned short* gB0 = whb  + (size_t)(col0 + srow)      * 1024 + ((sg ^ swz) * 8);
    unsigned short* wA0 = As + srow * 32 + ((sg ^ swz) * 8);
    unsigned short* wA1 = wA0 + 64 * 32;
    unsigned short* lB0 = Bs + tid * 8;
    const unsigned short* rA[4];
    const unsigned short* rB[4];
    #pragma unroll
    for (int i = 0; i < 4; ++i) {
        int ra = wy * 64 + i * 16 + l15;
        rA[i] = As + ra * 32 + ((quad ^ ((ra >> 1) & 3)) * 8);
        int rn = wx * 64 + i * 16 + l15;
        rB[i] = Bs + rn * 32 + ((quad ^ ((rn >> 1) & 3)) * 8);
    }
    f32x4 acc[4][4];
    #pragma unroll
    for (int i = 0; i < 4; ++i)
        #pragma unroll
        for (int j = 0; j < 4; ++j)
            acc[i][j] = (f32x4){0.f, 0.f, 0.f, 0.f};
    for (int k0 = 0; k0 < 1024; k0 += 32) {
        float4 va0 = *(const float4*)(gA0 + k0);
        float4 va1 = *(const float4*)(gA0 + k0 + 4);
        float4 va2 = *(const float4*)(gA1 + k0);
        float4 va3 = *(const float4*)(gA1 + k0 + 4);
        __syncthreads();
        gl2lds16(gB0 + k0, lB0);
        gl2lds16(gB0 + 65536 + k0, lB0 + 2048);
        uint4 pa0, pa1;
        pa0.x = pack2bf(va0.x, va0.y); pa0.y = pack2bf(va0.z, va0.w);
        pa0.z = pack2bf(va1.x, va1.y); pa0.w = pack2bf(va1.z, va1.w);
        pa1.x = pack2bf(va2.x, va2.y); pa1.y = pack2bf(va2.z, va2.w);
        pa1.z = pack2bf(va3.x, va3.y); pa1.w = pack2bf(va3.z, va3.w);
        *(uint4*)wA0 = pa0;
        *(uint4*)wA1 = pa1;
        __syncthreads();
        bf16x8s af[4], bfv[4];
        #pragma unroll
        for (int i = 0; i < 4; ++i) af[i]  = *(const bf16x8s*)rA[i];
        #pragma unroll
        for (int i = 0; i < 4; ++i) bfv[i] = *(const bf16x8s*)rB[i];
        #pragma unroll
        for (int mt = 0; mt < 4; ++mt)
            #pragma unroll
            for (int nt = 0; nt < 4; ++nt)
                acc[mt][nt] = __builtin_amdgcn_mfma_f32_16x16x32_bf16(af[mt], bfv[nt], acc[mt][nt], 0, 0, 0);
    }
    const int colb = col0 + wx * 64 + l15;
    float vwv[4], bv[4];
    #pragma unroll
    for (int nt = 0; nt < 4; ++nt) {
        vwv[nt] = vw[colb + nt * 16];
        bv[nt]  = bias[colb + nt * 16];
    }
    const int rowb = row0 + wy * 64 + quad * 4;
    const int colp = cb * 2 + wx;
    #pragma unroll
    for (int mt = 0; mt < 4; ++mt) {
        #pragma unroll
        for (int r = 0; r < 4; ++r) {
            float p = 0.f;
            #pragma unroll
            for (int nt = 0; nt < 4; ++nt)
                p += tanh_fast(acc[mt][nt][r] + bv[nt]) * vwv[nt];
            p += __shfl_xor(p, 1);
            p += __shfl_xor(p, 2);
            p += __shfl_xor(p, 4);
            p += __shfl_xor(p, 8);
            if (l15 == 0) s_part[(size_t)(rowb + mt * 16 + r) * 16 + colp] = p;
        }
    }
}

// ---------- kernel 3: sum partials + masked softmax; also zeroes d_out ----------
// s_part is row-major [65536][16]: 64B/row, read as 4 contiguous float4 per l.
__global__ __launch_bounds__(512) void softmax_kernel(const float* __restrict__ s_part,
                                                      const int* __restrict__ mask,
                                                      float* __restrict__ a_buf,
                                                      float* __restrict__ out) {
    const int b    = blockIdx.x;
    const int t    = threadIdx.x;
    const int wave = t >> 6;
    const int lane = t & 63;
    // zero the output slice this batch will atomically accumulate into (kernel 4)
    ((float2*)(out + b * 1024))[t] = (float2){0.f, 0.f};
    __shared__ float redm[8];
    __shared__ float reds[8];
    float sv[4];
    float mx = -3.0e38f;
    #pragma unroll
    for (int j = 0; j < 4; ++j) {
        int l = t + j * 512;
        const float4* pr = (const float4*)(s_part + ((size_t)b * 2048 + l) * 16);
        float4 q0 = pr[0], q1 = pr[1], q2 = pr[2], q3 = pr[3];
        float v = (q0.x + q0.y + q0.z + q0.w) + (q1.x + q1.y + q1.z + q1.w)
                + (q2.x + q2.y + q2.z + q2.w) + (q3.x + q3.y + q3.z + q3.w);
        if (mask[b * 2048 + l] == 0) v -= 10000.f;
        sv[j] = v;
        mx = fmaxf(mx, v);
    }
    #pragma unroll
    for (int off = 32; off; off >>= 1) mx = fmaxf(mx, __shfl_xor(mx, off));
    if (lane == 0) redm[wave] = mx;
    __syncthreads();
    mx = redm[0];
    #pragma unroll
    for (int w = 1; w < 8; ++w) mx = fmaxf(mx, redm[w]);
    float sum = 0.f;
    #pragma unroll
    for (int j = 0; j < 4; ++j) {
        sv[j] = __expf(sv[j] - mx);
        sum += sv[j];
    }
    #pragma unroll
    for (int off = 32; off; off >>= 1) sum += __shfl_xor(sum, off);
    if (lane == 0) reds[wave] = sum;
    __syncthreads();
    sum = reds[0];
    #pragma unroll
    for (int w = 1; w < 8; ++w) sum += reds[w];
    float inv = 1.f / sum;
    #pragma unroll
    for (int j = 0; j < 4; ++j)
        a_buf[b * 2048 + t + j * 512] = sv[j] * inv;
}

// ---------- kernel 4a: r[b,i] = sum_l a[b,l]*h[b,l,i], bf16 h (halved read) ----------
__global__ __launch_bounds__(256) void r_bf16_kernel(const unsigned short* __restrict__ hb,
                                                     const float* __restrict__ a_buf,
                                                     float* __restrict__ out) {
    const int b  = blockIdx.x >> 5;
    const int lc = blockIdx.x & 31;
    const int t  = threadIdx.x;
    __shared__ float aw[64];
    if (t < 64) aw[t] = a_buf[b * 2048 + lc * 64 + t];
    __syncthreads();
    const uint2* hp = (const uint2*)(hb + (size_t)(b * 2048 + lc * 64) * 1024) + t;
    float a0 = 0.f, a1 = 0.f, a2 = 0.f, a3 = 0.f;
    #pragma unroll 8
    for (int l = 0; l < 64; ++l) {
        uint2 v = hp[(size_t)l * 256];
        float av = aw[l];
        a0 += av * __uint_as_float(v.x << 16);
        a1 += av * __uint_as_float(v.x & 0xffff0000u);
        a2 += av * __uint_as_float(v.y << 16);
        a3 += av * __uint_as_float(v.y & 0xffff0000u);
    }
    float* op = out + b * 1024 + t * 4;
    atomicAdd(op + 0, a0);
    atomicAdd(op + 1, a1);
    atomicAdd(op + 2, a2);
    atomicAdd(op + 3, a3);
}

// ---------- kernel 4b: fp32 fallback ----------
__global__ __launch_bounds__(256) void r_f32_kernel(const float* __restrict__ hmat,
                                                    const float* __restrict__ a_buf,
                                                    float* __restrict__ out) {
    const int b  = blockIdx.x >> 5;
    const int lc = blockIdx.x & 31;
    const int t  = threadIdx.x;
    __shared__ float aw[64];
    if (t < 64) aw[t] = a_buf[b * 2048 + lc * 64 + t];
    __syncthreads();
    const float4* hp = (const float4*)hmat + (size_t)(b * 2048 + lc * 64) * 256;
    float ax = 0.f, ay = 0.f, az = 0.f, aq = 0.f;
    #pragma unroll 8
    for (int l = 0; l < 64; ++l) {
        float4 hv = hp[(size_t)l * 256 + t];
        float av = aw[l];
        ax += av * hv.x; ay += av * hv.y; az += av * hv.z; aq += av * hv.w;
    }
    float* op = out + b * 1024 + t * 4;
    atomicAdd(op + 0, ax);
    atomicAdd(op + 1, ay);
    atomicAdd(op + 2, az);
    atomicAdd(op + 3, aq);
}

// ---------- launch (4 dispatches, no memsets) ----------
extern "C" void kernel_launch(void* const* d_in, const int* in_sizes, int n_in,
                              void* d_out, int out_size, void* d_ws, size_t ws_size,
                              hipStream_t stream) {
    const float* h    = (const float*)d_in[0];
    const int*   mask = (const int*)d_in[1];
    const float* ln_w = (const float*)d_in[2];
    const float* ln_b = (const float*)d_in[3];
    const float* v_w  = (const float*)d_in[4];
    const float* vq   = (const float*)d_in[5];
    float* out = (float*)d_out;

    char* ws = (char*)d_ws;
    unsigned short* whb = (unsigned short*)(ws + WHB_OFF);
    float* bias         = (float*)(ws + BIAS_OFF);
    float* s_part       = (float*)(ws + SPART_OFF);
    float* a_buf        = (float*)(ws + ABUF_OFF);
    unsigned short* hb  = (unsigned short*)(ws + HB_OFF);

    const bool use_bf16_h = (ws_size >= WS_NEED_BF16);

    prep_kernel<<<1024, 256, 0, stream>>>(ln_w, ln_b, vq, whb, bias);
    if (use_bf16_h) {
        gemm256_fused_kernel<<<(NROWS / 256) * (HID / 128), 512, 0, stream>>>(h, whb, bias, v_w, s_part, hb);
        softmax_kernel<<<BATCH, 512, 0, stream>>>(s_part, mask, a_buf, out);
        r_bf16_kernel<<<BATCH * 32, 256, 0, stream>>>(hb, a_buf, out);
    } else {
        gemm_f32_kernel<<<(NROWS / 128) * (HID / 128), 256, 0, stream>>>(h, whb, bias, v_w, s_part);
        softmax_kernel<<<BATCH, 512, 0, stream>>>(s_part, mask, a_buf, out);
        r_f32_kernel<<<BATCH * 32, 256, 0, stream>>>(h, a_buf, out);
    }
}